// Round 2
// baseline (795.874 us; speedup 1.0000x reference)
//
#include <hip/hip_runtime.h>
#include <hip/hip_bf16.h>

// BatchedLoRA: out[t,n,o] = 2.0 * sum_r (sum_d x[t,d]*A[n,r,d]) * B[n,o,r]
// T=8192, D_IN=D_OUT=2048, RANK=64, NEXP=8
//
// Split-bf16 (hi/lo) MFMA path, 3-term: v*w ~= vh*wh + vh*wl + vl*wh.
// Stage 1 (x·A^T): split-K over the 3 terms (blockIdx.z), fp32 partials,
// combine kernel sums + re-splits a_down into ADh/ADl bf16 planes.
// Stage 2 (a_down·B^T per expert): 3 sequential K=64 core calls into one
// accumulator, fused *2.0, nontemporal 512MB out write.

#define T_TOK 8192
#define DIN   2048
#define DOUT  2048
#define RANK  64
#define NEXP  8
#define NR    (NEXP * RANK)   // 512

typedef __bf16 bf16;
typedef __attribute__((ext_vector_type(8))) __bf16 bf16x8;
typedef __attribute__((ext_vector_type(8))) float f32x8;
typedef __attribute__((ext_vector_type(4))) float f32x4;

#define ASYNC16(ldsdst, gsrc)                                                  \
  __builtin_amdgcn_global_load_lds(                                            \
      (const __attribute__((address_space(1))) void*)(gsrc),                   \
      (__attribute__((address_space(3))) void*)(ldsdst), 16, 0, 0)

__device__ __forceinline__ void split1(float v, bf16& h, bf16& l) {
  h = (bf16)v;               // RNE
  l = (bf16)(v - (float)h);  // residual
}

// ---- split kernels: fp32 -> hi/lo bf16 planes --------------------------

// generic: src [n8*8] fp32 -> H, L bf16 planes (same flat layout)
__global__ __launch_bounds__(256) void split_kernel(
    const float* __restrict__ src, bf16* __restrict__ H, bf16* __restrict__ L) {
  size_t u = (size_t)blockIdx.x * 256 + threadIdx.x;  // one 8-elem unit
  f32x8 v = *(const f32x8*)(src + u * 8);
  bf16x8 h, l;
#pragma unroll
  for (int e = 0; e < 8; ++e) {
    bf16 hh, ll;
    split1(v[e], hh, ll);
    h[e] = hh;
    l[e] = ll;
  }
  *(bf16x8*)(H + u * 8) = h;
  *(bf16x8*)(L + u * 8) = l;
}

// combine: a_down = P0+P1+P2 (fp32), re-split into ADh/ADl ([8192][512])
__global__ __launch_bounds__(256) void combine_kernel(
    const float* __restrict__ P, bf16* __restrict__ ADh,
    bf16* __restrict__ ADl) {
  size_t u = (size_t)blockIdx.x * 256 + threadIdx.x;
  const size_t plane = (size_t)T_TOK * NR;  // 4,194,304
  f32x8 v0 = *(const f32x8*)(P + u * 8);
  f32x8 v1 = *(const f32x8*)(P + plane + u * 8);
  f32x8 v2 = *(const f32x8*)(P + 2 * plane + u * 8);
  bf16x8 h, l;
#pragma unroll
  for (int e = 0; e < 8; ++e) {
    float s = v0[e] + v1[e] + v2[e];
    bf16 hh, ll;
    split1(s, hh, ll);
    h[e] = hh;
    l[e] = ll;
  }
  *(bf16x8*)(ADh + u * 8) = h;
  *(bf16x8*)(ADl + u * 8) = l;
}

// ---- shared 128x128 bt-GEMM core (m97 structure) -----------------------
// A [M][K] row-major (lda), B [N][K] row-major (ldb), K%32==0.
// 4 waves, each owns a 64x64 quadrant as 4x4 frags of 16x16x32.

template <int KTOT>
__device__ __forceinline__ void gemm_core(const bf16* __restrict__ Ag,
                                          size_t lda,
                                          const bf16* __restrict__ Bg,
                                          size_t ldb, int m0, int n0, int tid,
                                          bf16* sA, bf16* sB,
                                          f32x4 acc[4][4]) {
  const int wid = tid >> 6, lane = tid & 63;
  const int wm = wid >> 1, wn = wid & 1;
  const int lrow = lane & 15, lk = (lane >> 4) << 3;

  for (int k0 = 0; k0 < KTOT; k0 += 32) {
    __syncthreads();  // previous tile fully consumed
#pragma unroll
    for (int it = 0; it < 2; ++it) {
      int chunk = (wid << 1) + it;  // 8 chunks of 1KB per tile
      int u = (chunk << 6) + lane;  // 16B unit id, 0..511
      int row = u >> 2;             // 4 units per 64B row
      int kc = (u & 3) << 3;        // k offset in elems
      ASYNC16(sA + chunk * 512, Ag + (size_t)(m0 + row) * lda + k0 + kc);
      ASYNC16(sB + chunk * 512, Bg + (size_t)(n0 + row) * ldb + k0 + kc);
    }
    __syncthreads();  // compiler drains vmcnt before barrier

    bf16x8 af[4], bfr[4];
#pragma unroll
    for (int i = 0; i < 4; ++i) {
      af[i] = *(const bf16x8*)&sA[(wm * 64 + i * 16 + lrow) * 32 + lk];
      bfr[i] = *(const bf16x8*)&sB[(wn * 64 + i * 16 + lrow) * 32 + lk];
    }
#pragma unroll
    for (int i = 0; i < 4; ++i)
#pragma unroll
      for (int j = 0; j < 4; ++j)
        acc[i][j] = __builtin_amdgcn_mfma_f32_16x16x32_bf16(af[i], bfr[j],
                                                            acc[i][j], 0, 0, 0);
  }
}

// stage 1: P[z] = Xplane[z] * Aplane[z]^T  (z = term, K=2048 each)
__global__ __launch_bounds__(256) void gemm1_kernel(
    const bf16* __restrict__ Xh, const bf16* __restrict__ Xl,
    const bf16* __restrict__ Ah, const bf16* __restrict__ Al,
    float* __restrict__ P) {
  __shared__ __attribute__((aligned(16))) bf16 sA[128 * 32];
  __shared__ __attribute__((aligned(16))) bf16 sB[128 * 32];
  const f32x4 zero = {0.0f, 0.0f, 0.0f, 0.0f};
  f32x4 acc[4][4];
#pragma unroll
  for (int i = 0; i < 4; ++i)
#pragma unroll
    for (int j = 0; j < 4; ++j) acc[i][j] = zero;

  const int tid = threadIdx.x;
  const int z = blockIdx.z;
  const int m0 = blockIdx.y * 128, n0 = blockIdx.x * 128;
  const bf16* Xg = (z == 2) ? Xl : Xh;             // terms: hh, hl, lh
  const bf16* Ag = (z == 1) ? Al : Ah;
  gemm_core<DIN>(Xg, DIN, Ag, DIN, m0, n0, tid, sA, sB, acc);

  const int wid = tid >> 6, lane = tid & 63;
  const int wm = wid >> 1, wn = wid & 1;
  float* Pz = P + (size_t)z * T_TOK * NR;
  // C/D layout (16x16x32): col = lane&15, row = (lane>>4)*4 + reg
#pragma unroll
  for (int i = 0; i < 4; ++i) {
    int tb = m0 + wm * 64 + i * 16 + ((lane >> 4) << 2);
#pragma unroll
    for (int j = 0; j < 4; ++j) {
      int nr = n0 + wn * 64 + j * 16 + (lane & 15);
#pragma unroll
      for (int reg = 0; reg < 4; ++reg)
        Pz[(size_t)(tb + reg) * NR + nr] = acc[i][j][reg];
    }
  }
}

// stage 2: out[t,nx,o] = 2 * (ADh.Bh + ADh.Bl + ADl.Bh) per expert (K=64 each)
__global__ __launch_bounds__(256) void gemm2_kernel(
    const bf16* __restrict__ ADh, const bf16* __restrict__ ADl,
    const bf16* __restrict__ Bh, const bf16* __restrict__ Bl,
    float* __restrict__ out) {
  __shared__ __attribute__((aligned(16))) bf16 sA[128 * 32];
  __shared__ __attribute__((aligned(16))) bf16 sB[128 * 32];
  const f32x4 zero = {0.0f, 0.0f, 0.0f, 0.0f};
  f32x4 acc[4][4];
#pragma unroll
  for (int i = 0; i < 4; ++i)
#pragma unroll
    for (int j = 0; j < 4; ++j) acc[i][j] = zero;

  const int tid = threadIdx.x;
  const int nx = blockIdx.z;  // expert
  const int m0 = blockIdx.y * 128, o0 = blockIdx.x * 128;
  const bf16* Ah_ = ADh + (size_t)nx * RANK;        // row stride NR
  const bf16* Al_ = ADl + (size_t)nx * RANK;
  const bf16* Bh_ = Bh + (size_t)nx * DOUT * RANK;  // [2048][64]
  const bf16* Bl_ = Bl + (size_t)nx * DOUT * RANK;
  gemm_core<RANK>(Ah_, NR, Bh_, RANK, m0, o0, tid, sA, sB, acc);
  gemm_core<RANK>(Ah_, NR, Bl_, RANK, m0, o0, tid, sA, sB, acc);
  gemm_core<RANK>(Al_, NR, Bh_, RANK, m0, o0, tid, sA, sB, acc);

  const int wid = tid >> 6, lane = tid & 63;
  const int wm = wid >> 1, wn = wid & 1;
#pragma unroll
  for (int i = 0; i < 4; ++i) {
    int tb = m0 + wm * 64 + i * 16 + ((lane >> 4) << 2);
#pragma unroll
    for (int j = 0; j < 4; ++j) {
      int o = o0 + wn * 64 + j * 16 + (lane & 15);
#pragma unroll
      for (int reg = 0; reg < 4; ++reg)
        __builtin_nontemporal_store(
            2.0f * acc[i][j][reg],
            &out[((size_t)(tb + reg) * NEXP + nx) * DOUT + o]);
    }
  }
}

// ---- launch ------------------------------------------------------------

extern "C" void kernel_launch(void* const* d_in, const int* in_sizes, int n_in,
                              void* d_out, int out_size, void* d_ws,
                              size_t ws_size, hipStream_t stream) {
  const float* x = (const float*)d_in[0];
  const float* A = (const float*)d_in[1];
  const float* B = (const float*)d_in[2];
  float* out = (float*)d_out;
  char* ws = (char*)d_ws;

  // workspace layout (bytes):
  //   Xh/Xl : [8192][2048] bf16  = 33,554,432 each
  //   Ah/Al : [512][2048]  bf16  =  2,097,152 each
  //   Bh/Bl : [8][2048][64] bf16 =  2,097,152 each
  //   P     : [3][8192][512] f32 = 50,331,648
  //   ADh/ADl:[8192][512]  bf16  =  8,388,608 each      total 142,606,336
  bf16* Xh = (bf16*)(ws);
  bf16* Xl = (bf16*)(ws + 33554432ull);
  bf16* Ah = (bf16*)(ws + 67108864ull);
  bf16* Al = (bf16*)(ws + 69206016ull);
  bf16* Bh = (bf16*)(ws + 71303168ull);
  bf16* Bl = (bf16*)(ws + 73400320ull);
  float* P = (float*)(ws + 75497472ull);
  bf16* ADh = (bf16*)(ws + 125829120ull);
  bf16* ADl = (bf16*)(ws + 134217728ull);

  split_kernel<<<8192, 256, 0, stream>>>(x, Xh, Xl);  // 16.8M elems
  split_kernel<<<512, 256, 0, stream>>>(A, Ah, Al);   // 1.05M elems
  split_kernel<<<512, 256, 0, stream>>>(B, Bh, Bl);   // 1.05M elems
  gemm1_kernel<<<dim3(4, 64, 3), 256, 0, stream>>>(Xh, Xl, Ah, Al, P);
  combine_kernel<<<2048, 256, 0, stream>>>(P, ADh, ADl);
  gemm2_kernel<<<dim3(16, 64, 8), 256, 0, stream>>>(ADh, ADl, Bh, Bl, out);
}

// Round 4
// 770.394 us; speedup vs baseline: 1.0331x; 1.0331x over previous
//
#include <hip/hip_runtime.h>
#include <hip/hip_bf16.h>

// BatchedLoRA: out[t,n,o] = 2.0 * sum_r (sum_d x[t,d]*A[n,r,d]) * B[n,o,r]
// T=8192, D_IN=D_OUT=2048, RANK=64, NEXP=8
//
// Split-bf16 3-term path: v*w ~= vh*wh + vh*wl + vl*wh.
// 1) split_all: x->Xh/Xl, A->Ah/Al, B->B2=[bh|bl|bh] (K-stacked, 192)
// 2) gemm1: split-K over terms (z in grid), fp32 partials P[3][T][512]
// 3) combine: a_down = P0+P1+P2, re-split, write AD2=[adh|adh|adl] (192)
// 4) gemm2: per-expert K=192 bt-GEMM, fused *2.0, nontemporal out write
// XCD-aware block swizzle on both GEMMs (grids divide by 8 exactly).

#define T_TOK 8192
#define DIN   2048
#define RANK  64
#define NEXP  8
#define NR    512            // NEXP*RANK
#define K2    192            // stacked stage-2 K
#define LD_AD (NEXP * K2)    // 1536

typedef __bf16 bf16;
typedef __attribute__((ext_vector_type(8))) __bf16 bf16x8;
typedef __attribute__((ext_vector_type(8))) float f32x8;
typedef __attribute__((ext_vector_type(4))) float f32x4;

#define ASYNC16(ldsdst, gsrc)                                                  \
  __builtin_amdgcn_global_load_lds(                                            \
      (const __attribute__((address_space(1))) void*)(gsrc),                   \
      (__attribute__((address_space(3))) void*)(ldsdst), 16, 0, 0)

__device__ __forceinline__ void split1(float v, bf16& h, bf16& l) {
  h = (bf16)v;               // RNE
  l = (bf16)(v - (float)h);  // exact residual in fp32
}

// ---- fused split: x, A -> hi/lo planes; B -> stacked B2 ----------------
__global__ __launch_bounds__(256) void split_all_kernel(
    const float* __restrict__ x, const float* __restrict__ A,
    const float* __restrict__ B, bf16* __restrict__ Xh, bf16* __restrict__ Xl,
    bf16* __restrict__ Ah, bf16* __restrict__ Al, bf16* __restrict__ B2) {
  int bid = blockIdx.x;
  if (bid < 8192) {  // x: 16.8M elems, plain planes
    size_t u = (size_t)bid * 256 + threadIdx.x;
    f32x8 v = *(const f32x8*)(x + u * 8);
    bf16x8 h, l;
#pragma unroll
    for (int e = 0; e < 8; ++e) { bf16 hh, ll; split1(v[e], hh, ll); h[e] = hh; l[e] = ll; }
    *(bf16x8*)(Xh + u * 8) = h;
    *(bf16x8*)(Xl + u * 8) = l;
  } else if (bid < 8704) {  // A: 1.05M elems, plain planes
    size_t u = (size_t)(bid - 8192) * 256 + threadIdx.x;
    f32x8 v = *(const f32x8*)(A + u * 8);
    bf16x8 h, l;
#pragma unroll
    for (int e = 0; e < 8; ++e) { bf16 hh, ll; split1(v[e], hh, ll); h[e] = hh; l[e] = ll; }
    *(bf16x8*)(Ah + u * 8) = h;
    *(bf16x8*)(Al + u * 8) = l;
  } else {  // B [8*2048][64] -> B2 [8*2048][192] = [bh|bl|bh]
    size_t u = (size_t)(bid - 8704) * 256 + threadIdx.x;  // 8-elem units
    size_t no = u >> 3;
    int ku = (int)(u & 7);
    f32x8 v = *(const f32x8*)(B + no * 64 + ku * 8);
    bf16x8 h, l;
#pragma unroll
    for (int e = 0; e < 8; ++e) { bf16 hh, ll; split1(v[e], hh, ll); h[e] = hh; l[e] = ll; }
    bf16* row = B2 + no * K2 + ku * 8;
    *(bf16x8*)(row) = h;
    *(bf16x8*)(row + RANK) = l;
    *(bf16x8*)(row + 2 * RANK) = h;
  }
}

// ---- combine: a_down = sum of 3 partials, re-split into AD2 ------------
__global__ __launch_bounds__(256) void combine_kernel(
    const float* __restrict__ P, bf16* __restrict__ AD2) {
  size_t u = (size_t)blockIdx.x * 256 + threadIdx.x;  // 524288 units
  const size_t plane = (size_t)T_TOK * NR;
  f32x8 v0 = *(const f32x8*)(P + u * 8);
  f32x8 v1 = *(const f32x8*)(P + plane + u * 8);
  f32x8 v2 = *(const f32x8*)(P + 2 * plane + u * 8);
  bf16x8 h, l;
#pragma unroll
  for (int e = 0; e < 8; ++e) {
    float s = v0[e] + v1[e] + v2[e];
    bf16 hh, ll;
    split1(s, hh, ll);
    h[e] = hh; l[e] = ll;
  }
  size_t t = u >> 6;                  // 64 units per token
  int v = (int)(u & 63);
  int nx = v >> 3, r8 = (v & 7) << 3;
  bf16* q = AD2 + ((size_t)t * NEXP + nx) * K2 + r8;
  *(bf16x8*)(q) = h;                  // pairs bh
  *(bf16x8*)(q + RANK) = h;           // pairs bl
  *(bf16x8*)(q + 2 * RANK) = l;       // pairs bh
}

// ---- 128x128 bt-GEMM core (m97 structure), LDS owned internally --------
template <int KTOT>
__device__ __forceinline__ void gemm_bt(const bf16* __restrict__ Ag, int lda,
                                        const bf16* __restrict__ Bg, int ldb,
                                        int m0, int n0, f32x4 acc[4][4]) {
  __shared__ __attribute__((aligned(16))) bf16 sA[128 * 32];
  __shared__ __attribute__((aligned(16))) bf16 sB[128 * 32];
  const int tid = threadIdx.x;
  const int wid = tid >> 6, lane = tid & 63;
  const int wm = wid >> 1, wn = wid & 1;
  const int lrow = lane & 15, lk = (lane >> 4) << 3;

  for (int k0 = 0; k0 < KTOT; k0 += 32) {
    __syncthreads();  // previous tile fully consumed
#pragma unroll
    for (int it = 0; it < 2; ++it) {
      int chunk = (wid << 1) + it;  // 8 x 1KB chunks per tile
      int u = (chunk << 6) + lane;  // 16B unit id 0..511
      int row = u >> 2;             // 4 units per 64B row
      int kc = (u & 3) << 3;
      ASYNC16(sA + chunk * 512, Ag + (size_t)(m0 + row) * lda + k0 + kc);
      ASYNC16(sB + chunk * 512, Bg + (size_t)(n0 + row) * ldb + k0 + kc);
    }
    __syncthreads();  // compiler drains vmcnt before barrier

    bf16x8 af[4], bfr[4];
#pragma unroll
    for (int i = 0; i < 4; ++i) {
      af[i] = *(const bf16x8*)&sA[(wm * 64 + i * 16 + lrow) * 32 + lk];
      bfr[i] = *(const bf16x8*)&sB[(wn * 64 + i * 16 + lrow) * 32 + lk];
    }
#pragma unroll
    for (int i = 0; i < 4; ++i)
#pragma unroll
      for (int j = 0; j < 4; ++j)
        acc[i][j] = __builtin_amdgcn_mfma_f32_16x16x32_bf16(af[i], bfr[j],
                                                            acc[i][j], 0, 0, 0);
  }
}

// ---- stage 1: P[z] = Xplane[z] * Aplane[z]^T (K=2048 each) -------------
__global__ __launch_bounds__(256) void gemm1_kernel(
    const bf16* __restrict__ Xh, const bf16* __restrict__ Xl,
    const bf16* __restrict__ Ah, const bf16* __restrict__ Al,
    float* __restrict__ P) {
  // XCD swizzle: 768 blocks = 8 XCDs x 96. Same-XCD neighbors share m-slab
  // (n fastest), Ah/Al (2MB) stay L2-resident.
  int bid = blockIdx.x;
  int virt = (bid & 7) * 96 + (bid >> 3);
  int z = virt >> 8;            // 256 tiles per term
  int rem = virt & 255;
  int m0 = (rem >> 2) << 7;     // 64 m-tiles
  int n0 = (rem & 3) << 7;      // 4 n-tiles

  const bf16* Ag = (z == 2) ? Xl : Xh;  // terms: hh, hl, lh
  const bf16* Bg = (z == 1) ? Al : Ah;

  const f32x4 zero = {0.0f, 0.0f, 0.0f, 0.0f};
  f32x4 acc[4][4];
#pragma unroll
  for (int i = 0; i < 4; ++i)
#pragma unroll
    for (int j = 0; j < 4; ++j) acc[i][j] = zero;

  gemm_bt<DIN>(Ag, DIN, Bg, DIN, m0, n0, acc);

  const int tid = threadIdx.x;
  const int wid = tid >> 6, lane = tid & 63;
  const int wm = wid >> 1, wn = wid & 1;
  float* Pz = P + (size_t)z * T_TOK * NR;
  // C/D layout (16x16x32): col = lane&15, row = (lane>>4)*4 + reg
#pragma unroll
  for (int i = 0; i < 4; ++i) {
    int tb = m0 + wm * 64 + i * 16 + ((lane >> 4) << 2);
#pragma unroll
    for (int j = 0; j < 4; ++j) {
      int nr = n0 + wn * 64 + j * 16 + (lane & 15);
#pragma unroll
      for (int reg = 0; reg < 4; ++reg)
        Pz[(size_t)(tb + reg) * NR + nr] = acc[i][j][reg];
    }
  }
}

// ---- stage 2: out = 2 * AD2 . B2^T per expert (K=192 stacked) ----------
__global__ __launch_bounds__(256) void gemm2_kernel(
    const bf16* __restrict__ AD2, const bf16* __restrict__ B2,
    float* __restrict__ out) {
  // XCD swizzle: 8192 blocks = 8 x 1024. o fastest (16 blocks share the
  // AD m-slab 393KB + per-expert B panel 786KB -> L2-resident), then nx, m.
  int bid = blockIdx.x;
  int virt = (bid & 7) * 1024 + (bid >> 3);
  int m = virt >> 7;
  int rem = virt & 127;
  int nx = rem >> 4, o = rem & 15;
  int m0 = m << 7, o0 = o << 7;

  const bf16* Ag = AD2 + (size_t)nx * K2;         // row stride LD_AD
  const bf16* Bg = B2 + (size_t)nx * 2048 * K2;   // [2048][192]

  const f32x4 zero = {0.0f, 0.0f, 0.0f, 0.0f};
  f32x4 acc[4][4];
#pragma unroll
  for (int i = 0; i < 4; ++i)
#pragma unroll
    for (int j = 0; j < 4; ++j) acc[i][j] = zero;

  gemm_bt<K2>(Ag, LD_AD, Bg, K2, m0, o0, acc);

  const int tid = threadIdx.x;
  const int wid = tid >> 6, lane = tid & 63;
  const int wm = wid >> 1, wn = wid & 1;
#pragma unroll
  for (int i = 0; i < 4; ++i) {
    int tb = m0 + wm * 64 + i * 16 + ((lane >> 4) << 2);
#pragma unroll
    for (int j = 0; j < 4; ++j) {
      int oc = o0 + wn * 64 + j * 16 + (lane & 15);
#pragma unroll
      for (int reg = 0; reg < 4; ++reg)
        __builtin_nontemporal_store(
            2.0f * acc[i][j][reg],
            &out[((size_t)(tb + reg) * NEXP + nx) * 2048 + oc]);
    }
  }
}

// ---- launch ------------------------------------------------------------
extern "C" void kernel_launch(void* const* d_in, const int* in_sizes, int n_in,
                              void* d_out, int out_size, void* d_ws,
                              size_t ws_size, hipStream_t stream) {
  const float* x = (const float*)d_in[0];
  const float* A = (const float*)d_in[1];
  const float* B = (const float*)d_in[2];
  float* out = (float*)d_out;
  char* ws = (char*)d_ws;

  // workspace (bytes):
  //   Xh @0        33,554,432      Xl @33,554,432   33,554,432
  //   Ah @67,108,864  2,097,152    Al @69,206,016    2,097,152
  //   B2 @71,303,168  6,291,456    P  @77,594,624   50,331,648
  //   AD2 @127,926,272 25,165,824            (end ~153 MB)
  bf16* Xh = (bf16*)(ws);
  bf16* Xl = (bf16*)(ws + 33554432ull);
  bf16* Ah = (bf16*)(ws + 67108864ull);
  bf16* Al = (bf16*)(ws + 69206016ull);
  bf16* B2 = (bf16*)(ws + 71303168ull);
  float* P = (float*)(ws + 77594624ull);
  bf16* AD2 = (bf16*)(ws + 127926272ull);

  split_all_kernel<<<9216, 256, 0, stream>>>(x, A, B, Xh, Xl, Ah, Al, B2);
  gemm1_kernel<<<768, 256, 0, stream>>>(Xh, Xl, Ah, Al, P);
  combine_kernel<<<2048, 256, 0, stream>>>(P, AD2);
  gemm2_kernel<<<8192, 256, 0, stream>>>(AD2, B2, out);
}